// Round 10
// baseline (354.614 us; speedup 1.0000x reference)
//
#include <hip/hip_runtime.h>
#include <hip/hip_bf16.h>
#include <math.h>

// Problem constants (B=4, H=W=64, C=128, DI=256, N=16, R=8, K=4)
// BATCHED over the 2 streams: 8 images, 32768 rows, 32 bk channel-groups.
#define DDIM 256
#define NCH  128
#define LCH  32

typedef __attribute__((ext_vector_type(8))) short bf8_t;
typedef __attribute__((ext_vector_type(4))) float f32x4;
typedef __attribute__((ext_vector_type(8))) unsigned short u16x8;
typedef _Float16 f16;
typedef __attribute__((ext_vector_type(2))) _Float16 f16x2;

__device__ __forceinline__ float silu_f(float x) {
    return x / (1.f + __expf(-x));
}
__device__ __forceinline__ float softplus_f(float x) {
    return fmaxf(x, 0.f) + __logf(1.f + __expf(-fabsf(x)));
}
__device__ __forceinline__ unsigned short f2b(float x) {
    union { __hip_bfloat16 h; unsigned short u; } v;
    v.h = __float2bfloat16(x);
    return v.u;
}
__device__ __forceinline__ float b2f(unsigned short u) {
    union { float f; unsigned int i; } v;
    v.i = ((unsigned int)u) << 16;
    return v.f;
}
__device__ __forceinline__ int perm_idx(int k, int l) {
    switch (k & 3) {
        case 0: return l;
        case 1: return ((l & 63) << 6) | (l >> 6);
        case 2: return 4095 - l;
        default: { int lr = 4095 - l; return ((lr & 63) << 6) | (lr >> 6); }
    }
}
// ---- packed f16 helpers -------------------------------------------------
__device__ __forceinline__ f16x2 pkrtz(float a, float b) {
    return __builtin_bit_cast(f16x2, __builtin_amdgcn_cvt_pkrtz(a, b));
}
__device__ __forceinline__ f16x2 bch(unsigned v) {
    return __builtin_bit_cast(f16x2, v);
}
__device__ __forceinline__ unsigned bcu(f16x2 v) {
    return __builtin_bit_cast(unsigned, v);
}
__device__ __forceinline__ f16x2 pk_fma_h(f16x2 a, f16x2 b, f16x2 c) {
    f16x2 d;
    asm("v_pk_fma_f16 %0, %1, %2, %3" : "=v"(d) : "v"(a), "v"(b), "v"(c));
    return d;
}
__device__ __forceinline__ float dot2_h(f16x2 a, f16x2 b, float c) {
    float d;
    asm("v_dot2_f32_f16 %0, %1, %2, %3" : "=v"(d) : "v"(a), "v"(b), "v"(c));
    return d;
}
__device__ __forceinline__ bool geom_check(const float* Alogs, int kd, float& a0) {
    a0 = -__expf(Alogs[(size_t)kd * 16]);
    bool g = true;
    #pragma unroll
    for (int n = 1; n < 16; ++n) {
        const float an = -__expf(Alogs[(size_t)kd * 16 + n]);
        const float rr = a0 * (float)(n + 1);
        g = g && (fabsf(an - rr) <= 1e-4f * fabsf(rr));
    }
    return g;
}

// ---------------------------------------------------------------------------
// Convert all 5 weight tensors fp32->bf16 in one launch.
// ---------------------------------------------------------------------------
__global__ __launch_bounds__(256) void cvt_all(
    const float* __restrict__ s0, const float* __restrict__ s1,
    const float* __restrict__ s2, const float* __restrict__ s3,
    const float* __restrict__ s4, unsigned short* __restrict__ w) {
    const int i = blockIdx.x * 256 + threadIdx.x;
    const float* src; size_t so, oo;
    if (i < 8192)       { src = s0; so = i;         oo = 0; }
    else if (i < 16384) { src = s1; so = i - 8192;  oo = 65536; }
    else if (i < 21504) { src = s2; so = i - 16384; oo = 131072; }
    else if (i < 25600) { src = s3; so = i - 21504; oo = 172032; }
    else if (i < 29696) { src = s4; so = i - 25600; oo = 204800; }
    else return;
    const float4 a = ((const float4*)src)[so * 2];
    const float4 b = ((const float4*)src)[so * 2 + 1];
    u16x8 r;
    r[0] = f2b(a.x); r[1] = f2b(a.y); r[2] = f2b(a.z); r[3] = f2b(a.w);
    r[4] = f2b(b.x); r[5] = f2b(b.y); r[6] = f2b(b.z); r[7] = f2b(b.w);
    *(u16x8*)(w + oo + so * 8) = r;
}

// ---------------------------------------------------------------------------
// bf16 MFMA GEMM (batched 2-stream): out[m,n] = sum_k A[m,k] * W[n,k].
// EPI=0: plain f32. EPI=1: in_proj split (xc f32 | silu->bf16 z).
// EPI=2: out_proj per-stream offset. EPI=3: f16 store (x_proj).
// ---------------------------------------------------------------------------
template <int EPI, bool AF32>
__global__ __launch_bounds__(256) void gemm_bf(
    const unsigned short* __restrict__ A,
    const float* __restrict__ Af0, const float* __restrict__ Af1,
    const unsigned short* __restrict__ W0, const unsigned short* __restrict__ W1,
    float* __restrict__ out0, unsigned short* __restrict__ out1b,
    int N, int K, int msplit) {
    __shared__ unsigned short As[128][40];
    __shared__ unsigned short Bs[128][40];
    const int tid = threadIdx.x;
    const int lane = tid & 63;
    const int wid = tid >> 6;
    const int wr = wid >> 1, wc = wid & 1;
    const int m0 = blockIdx.y << 7, n0 = blockIdx.x << 7;
    const int sidx = (m0 >= msplit) ? 1 : 0;
    const int rbase = sidx ? msplit : 0;
    const float* Af = sidx ? Af1 : Af0;
    const unsigned short* W = sidx ? W1 : W0;
    const int r = lane & 15, g = lane >> 4;
    f32x4 acc[4][4];
    #pragma unroll
    for (int i = 0; i < 4; ++i)
        #pragma unroll
        for (int j = 0; j < 4; ++j) acc[i][j] = (f32x4){0.f, 0.f, 0.f, 0.f};
    const int row0 = tid >> 2;       // 0..63
    const int cc = (tid & 3) << 3;   // 0,8,16,24

    for (int k0 = 0; k0 < K; k0 += 32) {
        #pragma unroll
        for (int h = 0; h < 2; ++h) {
            const int row = row0 + (h << 6);
            u16x8 va;
            if (AF32) {
                const float* ap = Af + (size_t)(m0 + row - rbase) * K + k0 + cc;
                const float4 a0 = *(const float4*)ap;
                const float4 a1 = *(const float4*)(ap + 4);
                va[0] = f2b(a0.x); va[1] = f2b(a0.y);
                va[2] = f2b(a0.z); va[3] = f2b(a0.w);
                va[4] = f2b(a1.x); va[5] = f2b(a1.y);
                va[6] = f2b(a1.z); va[7] = f2b(a1.w);
            } else {
                va = *(const u16x8*)(A + (size_t)(m0 + row) * K + k0 + cc);
            }
            *(u16x8*)(&As[row][cc]) = va;
            const int nrow = n0 + row;
            u16x8 vb = (u16x8){0, 0, 0, 0, 0, 0, 0, 0};
            if (nrow < N) vb = *(const u16x8*)(W + (size_t)nrow * K + k0 + cc);
            *(u16x8*)(&Bs[row][cc]) = vb;
        }
        __syncthreads();
        bf8_t af[4], bfr[4];
        #pragma unroll
        for (int i = 0; i < 4; ++i)
            af[i] = *(const bf8_t*)(&As[(wr << 6) + (i << 4) + r][g << 3]);
        #pragma unroll
        for (int j = 0; j < 4; ++j)
            bfr[j] = *(const bf8_t*)(&Bs[(wc << 6) + (j << 4) + r][g << 3]);
        #pragma unroll
        for (int i = 0; i < 4; ++i)
            #pragma unroll
            for (int j = 0; j < 4; ++j)
                acc[i][j] = __builtin_amdgcn_mfma_f32_16x16x32_bf16(
                    af[i], bfr[j], acc[i][j], 0, 0, 0);
        __syncthreads();
    }
    // epilogue: C/D layout col=lane&15, row=(lane>>4)*4+reg
    #pragma unroll
    for (int i = 0; i < 4; ++i) {
        const int mrow = m0 + (wr << 6) + (i << 4) + (g << 2);
        #pragma unroll
        for (int j = 0; j < 4; ++j) {
            const int col = n0 + (wc << 6) + (j << 4) + r;
            if (EPI != 1 && col >= N) continue;
            #pragma unroll
            for (int q = 0; q < 4; ++q) {
                const float v = acc[i][j][q];
                const int mm = mrow + q;
                if (EPI == 0) {
                    out0[(size_t)mm * N + col] = v;
                } else if (EPI == 1) {
                    if (col < 256) out0[((size_t)mm << 8) + col] = v;
                    else out1b[((size_t)mm << 8) + (col - 256)] = f2b(silu_f(v));
                } else if (EPI == 2) {
                    out0[(size_t)sidx * 2097152 +
                         ((size_t)(mm - rbase) << 7) + col] = v;
                } else {
                    ((f16*)out1b)[(size_t)mm * N + col] = (f16)v;
                }
            }
        }
    }
}

// ---------------------------------------------------------------------------
// Depthwise 3x3 conv (SAME) + bias + SiLU, batched; weights per stream.
// ---------------------------------------------------------------------------
__global__ __launch_bounds__(256) void dwconv_silu(
    const float* __restrict__ in,
    const float* __restrict__ w0, const float* __restrict__ b0,
    const float* __restrict__ w1, const float* __restrict__ b1,
    float* __restrict__ outf) {
    const int d = threadIdx.x;
    const int bp = blockIdx.x;            // [0, 32768)
    const int b = bp >> 12;               // [0, 8)
    const float* w = (b >= 4) ? w1 : w0;
    const float* bias = (b >= 4) ? b1 : b0;
    const int sp = bp & 4095;
    const int h = sp >> 6, wc = sp & 63;
    float acc = bias[d];
    #pragma unroll
    for (int kh = 0; kh < 3; ++kh) {
        const int hh = h + kh - 1;
        if (hh < 0 || hh >= 64) continue;
        #pragma unroll
        for (int kw = 0; kw < 3; ++kw) {
            const int ww = wc + kw - 1;
            if (ww < 0 || ww >= 64) continue;
            acc = fmaf(in[(size_t)(((b << 12) + (hh << 6) + ww)) * DDIM + d],
                       w[d * 9 + kh * 3 + kw], acc);
        }
    }
    outf[(size_t)bp * DDIM + d] = silu_f(acc);
}

// ---------------------------------------------------------------------------
// scan chain A (one chunk, one direction): compile-time stride SS, explicit
// register double-buffered prefetch of the proj row (3 uint4) + u.
// Writes h_end (f16) and cum delta.
// ---------------------------------------------------------------------------
template <int SS>
__device__ __forceinline__ void chainA(
    const int k, const int kd, const int bk, const int chunk, const int bpp0,
    const int d,
    const float* __restrict__ xc, const f16* __restrict__ proj,
    const float* __restrict__ Alogs, const float* __restrict__ dtw,
    const float* __restrict__ dtb,
    f16* __restrict__ hend, float* __restrict__ cumd) {
    float a0;
    const bool geom = geom_check(Alogs, kd, a0);
    const float4 w0f = *(const float4*)(dtw + (size_t)kd * 8);
    const float4 w1f = *(const float4*)(dtw + (size_t)kd * 8 + 4);
    const float bias = dtb[kd];
    float cum = 0.f;
    const size_t o32 = ((size_t)(chunk * 32 + bk) * DDIM + d) * 8;  // uint units

    if (geom) {
        const f16x2 wh[4] = {pkrtz(w0f.x, w0f.y), pkrtz(w0f.z, w0f.w),
                             pkrtz(w1f.x, w1f.y), pkrtz(w1f.z, w1f.w)};
        f16x2 h[8];
        #pragma unroll
        for (int j = 0; j < 8; ++j) h[j] = (f16x2){(f16)0.f, (f16)0.f};
        const unsigned* prow =
            (const unsigned*)(proj + (size_t)bpp0 * 160 + k * 40);
        const float* up = xc + (size_t)bpp0 * DDIM + d;
        uint4 dt_n = *(const uint4*)prow;
        uint4 B0_n = *(const uint4*)(prow + 4);
        uint4 B1_n = *(const uint4*)(prow + 8);
        float u_n = *up;
        #pragma unroll 4
        for (int t = 0; t < LCH; ++t) {
            const uint4 dt4 = dt_n, B0 = B0_n, B1 = B1_n;
            const float u = u_n;
            if (t < LCH - 1) {
                prow += SS * 80;
                up += (ptrdiff_t)SS * DDIM;
                dt_n = *(const uint4*)prow;
                B0_n = *(const uint4*)(prow + 4);
                B1_n = *(const uint4*)(prow + 8);
                u_n = *up;
            }
            float x = bias;
            x = dot2_h(bch(dt4.x), wh[0], x);
            x = dot2_h(bch(dt4.y), wh[1], x);
            x = dot2_h(bch(dt4.z), wh[2], x);
            x = dot2_h(bch(dt4.w), wh[3], x);
            const float delta = softplus_f(x);
            const float du = delta * u;
            cum += delta;
            const float e1 = __expf(delta * a0);
            const float e2 = e1 * e1;
            const f16x2 s2 = pkrtz(e2, e2);
            f16x2 dA[8];
            dA[0] = pkrtz(e1, e2);
            #pragma unroll
            for (int j = 1; j < 8; ++j) dA[j] = dA[j - 1] * s2;
            const f16x2 du2 = pkrtz(du, du);
            const unsigned Bw[8] = {B0.x, B0.y, B0.z, B0.w,
                                    B1.x, B1.y, B1.z, B1.w};
            #pragma unroll
            for (int j = 0; j < 8; ++j)
                h[j] = pk_fma_h(dA[j], h[j], du2 * bch(Bw[j]));
        }
        const uint4 s0 = make_uint4(bcu(h[0]), bcu(h[1]), bcu(h[2]), bcu(h[3]));
        const uint4 s1 = make_uint4(bcu(h[4]), bcu(h[5]), bcu(h[6]), bcu(h[7]));
        *(uint4*)((unsigned*)hend + o32) = s0;
        *(uint4*)((unsigned*)hend + o32 + 4) = s1;
    } else {
        float w8[8] = {w0f.x, w0f.y, w0f.z, w0f.w, w1f.x, w1f.y, w1f.z, w1f.w};
        float h[16];
        #pragma unroll
        for (int n = 0; n < 16; ++n) h[n] = 0.f;
        int bpp = bpp0;
        for (int t = 0; t < LCH; ++t) {
            const f16* pr = proj + (size_t)bpp * 160 + k * 40;
            float x = bias;
            #pragma unroll
            for (int r = 0; r < 8; ++r) x = fmaf((float)pr[r], w8[r], x);
            const float delta = softplus_f(x);
            const float u = xc[(size_t)bpp * DDIM + d];
            const float du = delta * u;
            cum += delta;
            #pragma unroll
            for (int n = 0; n < 16; ++n) {
                const float an = -__expf(Alogs[(size_t)kd * 16 + n]);
                h[n] = fmaf(__expf(delta * an), h[n], du * (float)pr[8 + n]);
            }
            bpp += SS;
        }
        #pragma unroll
        for (int n = 0; n < 16; ++n)
            ((f16*)hend)[o32 * 2 + n] = (f16)h[n];
    }
    cumd[(size_t)(chunk * 32 + bk) * DDIM + d] = cum;
}

// Pair-fused scanA: chain (k=PAIR, chunk c, +S) then (k=PAIR+2, chunk
// NCH-1-c, -S) over the same 32-position linear window.
// blockIdx = b*NCH + c, b in [0,8). S = 1 (PAIR=0) or 64 (PAIR=1).
template <int PAIR>
__global__ __launch_bounds__(256) void scanA2T(
    const float* __restrict__ xc, const f16* __restrict__ proj,
    const float* __restrict__ Alogs, const float* __restrict__ dtw,
    const float* __restrict__ dtb,
    f16* __restrict__ hend, float* __restrict__ cumd) {
    constexpr int S = (PAIR == 0) ? 1 : 64;
    const int d = threadIdx.x;
    const int blk = blockIdx.x;
    const int c = blk & (NCH - 1);
    const int b = blk >> 7;
    const int p0 = perm_idx(PAIR, c * LCH);
    const int bpp0 = (b << 12) + p0;
    chainA<S>(PAIR, (PAIR << 8) + d, (b << 2) + PAIR, c, bpp0, d,
              xc, proj, Alogs, dtw, dtb, hend, cumd);
    chainA<-S>(PAIR + 2, ((PAIR + 2) << 8) + d, (b << 2) + PAIR + 2,
               NCH - 1 - c, bpp0 + 31 * S, d,
               xc, proj, Alogs, dtw, dtb, hend, cumd);
}

// ---------------------------------------------------------------------------
// Scan phase B: inter-chunk recurrence over 131072 states, IN PLACE on the
// fp16 buffer (read hend[c], then overwrite slot c with H0[c]).
// ---------------------------------------------------------------------------
__global__ __launch_bounds__(256) void scanB(
    f16* __restrict__ hh, const float* __restrict__ cumd,
    const float* __restrict__ Alogs) {
    const int tid = blockIdx.x * 256 + threadIdx.x;   // [0, 131072)
    const int n = tid & 15;
    const int d = (tid >> 4) & 255;
    const int bk = tid >> 12;
    const int k = bk & 3;
    const float a = -__expf(Alogs[(size_t)(((k << 8) + d)) * 16 + n]);
    const int cdix = tid >> 4;                        // bk*256+d
    float H = 0.f;
    for (int c = 0; c < NCH; c += 4) {
        float tmp[4], cd[4];
        #pragma unroll
        for (int j = 0; j < 4; ++j) {
            tmp[j] = (float)hh[(size_t)(c + j) * 131072 + tid];
            cd[j] = cumd[(size_t)(c + j) * 8192 + cdix];
        }
        #pragma unroll
        for (int j = 0; j < 4; ++j) {
            hh[(size_t)(c + j) * 131072 + tid] = (f16)H;
            H = fmaf(__expf(cd[j] * a), H, tmp[j]);
        }
    }
}

// ---------------------------------------------------------------------------
// scan chain C (one chunk, one direction): compile-time stride SS, register
// double-buffered prefetch of proj row (5 uint4) + u. EMIT=0: y->ybuf[t][d].
// EMIT=1: emit ybuf[31-t][d] + y to ysp (pointer-strided).
// ---------------------------------------------------------------------------
template <int SS, int EMIT>
__device__ __forceinline__ void chainC(
    const int k, const int kd, const int bk, const int chunk, const int bpp0,
    const int d,
    const float* __restrict__ xc, const f16* __restrict__ proj,
    const float* __restrict__ Alogs, const float* __restrict__ dtw,
    const float* __restrict__ dtb, const float* __restrict__ Dsv,
    const f16* __restrict__ H0, f16* __restrict__ ysp,
    f16 (*ybuf)[256], const size_t planeBase) {
    float a0;
    const bool geom = geom_check(Alogs, kd, a0);
    const float4 w0f = *(const float4*)(dtw + (size_t)kd * 8);
    const float4 w1f = *(const float4*)(dtw + (size_t)kd * 8 + 4);
    const float bias = dtb[kd];
    const float Dd = Dsv[kd];
    const size_t o32 = ((size_t)(chunk * 32 + bk) * DDIM + d) * 8;  // uint units
    const int p0 = bpp0 & 4095;
    f16* yp = ysp + planeBase + (size_t)p0 * DDIM + d;

    if (geom) {
        const f16x2 wh[4] = {pkrtz(w0f.x, w0f.y), pkrtz(w0f.z, w0f.w),
                             pkrtz(w1f.x, w1f.y), pkrtz(w1f.z, w1f.w)};
        f16x2 h[8];
        {
            const uint4 r0 = *(const uint4*)((const unsigned*)H0 + o32);
            const uint4 r1 = *(const uint4*)((const unsigned*)H0 + o32 + 4);
            h[0] = bch(r0.x); h[1] = bch(r0.y); h[2] = bch(r0.z); h[3] = bch(r0.w);
            h[4] = bch(r1.x); h[5] = bch(r1.y); h[6] = bch(r1.z); h[7] = bch(r1.w);
        }
        const unsigned* prow =
            (const unsigned*)(proj + (size_t)bpp0 * 160 + k * 40);
        const float* up = xc + (size_t)bpp0 * DDIM + d;
        uint4 dt_n = *(const uint4*)prow;
        uint4 B0_n = *(const uint4*)(prow + 4);
        uint4 B1_n = *(const uint4*)(prow + 8);
        uint4 C0_n = *(const uint4*)(prow + 12);
        uint4 C1_n = *(const uint4*)(prow + 16);
        float u_n = *up;
        #pragma unroll 4
        for (int t = 0; t < LCH; ++t) {
            const uint4 dt4 = dt_n, B0 = B0_n, B1 = B1_n, C0 = C0_n, C1 = C1_n;
            const float u = u_n;
            if (t < LCH - 1) {
                prow += SS * 80;
                up += (ptrdiff_t)SS * DDIM;
                dt_n = *(const uint4*)prow;
                B0_n = *(const uint4*)(prow + 4);
                B1_n = *(const uint4*)(prow + 8);
                C0_n = *(const uint4*)(prow + 12);
                C1_n = *(const uint4*)(prow + 16);
                u_n = *up;
            }
            float x = bias;
            x = dot2_h(bch(dt4.x), wh[0], x);
            x = dot2_h(bch(dt4.y), wh[1], x);
            x = dot2_h(bch(dt4.z), wh[2], x);
            x = dot2_h(bch(dt4.w), wh[3], x);
            const float delta = softplus_f(x);
            const float du = delta * u;
            const float e1 = __expf(delta * a0);
            const float e2 = e1 * e1;
            const f16x2 s2 = pkrtz(e2, e2);
            f16x2 dA[8];
            dA[0] = pkrtz(e1, e2);
            #pragma unroll
            for (int j = 1; j < 8; ++j) dA[j] = dA[j - 1] * s2;
            const f16x2 du2 = pkrtz(du, du);
            const unsigned Bw[8] = {B0.x, B0.y, B0.z, B0.w,
                                    B1.x, B1.y, B1.z, B1.w};
            const unsigned Cw[8] = {C0.x, C0.y, C0.z, C0.w,
                                    C1.x, C1.y, C1.z, C1.w};
            float y = 0.f;
            #pragma unroll
            for (int j = 0; j < 8; ++j) {
                h[j] = pk_fma_h(dA[j], h[j], du2 * bch(Bw[j]));
                y = dot2_h(h[j], bch(Cw[j]), y);
            }
            y = fmaf(Dd, u, y);
            if (EMIT == 0) ybuf[t][d] = (f16)y;
            else *yp = (f16)(y + (float)ybuf[31 - t][d]);
            yp += (ptrdiff_t)SS * DDIM;
        }
    } else {
        float w8[8] = {w0f.x, w0f.y, w0f.z, w0f.w, w1f.x, w1f.y, w1f.z, w1f.w};
        float h[16];
        #pragma unroll
        for (int n = 0; n < 16; ++n)
            h[n] = (float)((const f16*)H0)[o32 * 2 + n];
        int bpp = bpp0;
        for (int t = 0; t < LCH; ++t) {
            const f16* pr = proj + (size_t)bpp * 160 + k * 40;
            float x = bias;
            #pragma unroll
            for (int r = 0; r < 8; ++r) x = fmaf((float)pr[r], w8[r], x);
            const float delta = softplus_f(x);
            const float u = xc[(size_t)bpp * DDIM + d];
            const float du = delta * u;
            float y = 0.f;
            #pragma unroll
            for (int n = 0; n < 16; ++n) {
                const float an = -__expf(Alogs[(size_t)kd * 16 + n]);
                h[n] = fmaf(__expf(delta * an), h[n], du * (float)pr[8 + n]);
                y = fmaf(h[n], (float)pr[24 + n], y);
            }
            y = fmaf(Dd, u, y);
            if (EMIT == 0) ybuf[t][d] = (f16)y;
            else *yp = (f16)(y + (float)ybuf[31 - t][d]);
            yp += (ptrdiff_t)SS * DDIM;
            bpp += SS;
        }
    }
}

// Pair-fused scanC: (k=PAIR, chunk c, +S) buffers y; (k=PAIR+2, chunk
// NCH-1-c, -S) emits pair-sums. ysp has 16 f16 planes (b*2+PAIR).
// blockIdx = b*NCH + c, b in [0,8).
template <int PAIR>
__global__ __launch_bounds__(256) void scanC2T(
    const float* __restrict__ xc, const f16* __restrict__ proj,
    const float* __restrict__ Alogs, const float* __restrict__ dtw,
    const float* __restrict__ dtb, const float* __restrict__ Dsv,
    const f16* __restrict__ H0, f16* __restrict__ ysp) {
    __shared__ f16 ybuf[LCH][256];
    constexpr int S = (PAIR == 0) ? 1 : 64;
    const int d = threadIdx.x;
    const int blk = blockIdx.x;
    const int c = blk & (NCH - 1);
    const int b = blk >> 7;
    const int p0 = perm_idx(PAIR, c * LCH);
    const int bpp0 = (b << 12) + p0;
    const size_t planeBase = (size_t)(b * 2 + PAIR) << 20;
    chainC<S, 0>(PAIR, (PAIR << 8) + d, (b << 2) + PAIR, c, bpp0, d,
                 xc, proj, Alogs, dtw, dtb, Dsv, H0, ysp, ybuf, planeBase);
    chainC<-S, 1>(PAIR + 2, ((PAIR + 2) << 8) + d, (b << 2) + PAIR + 2,
                  NCH - 1 - c, bpp0 + 31 * S, d,
                  xc, proj, Alogs, dtw, dtb, Dsv, H0, ysp, ybuf, planeBase);
}

// ---------------------------------------------------------------------------
// Merge 2 pair-planes (f16) + LayerNorm(D) + gate with bf16 z -> bf16 yz.
// ---------------------------------------------------------------------------
__global__ __launch_bounds__(256) void merge_ln(
    const f16* __restrict__ ysp, const unsigned short* __restrict__ z,
    const float* __restrict__ lnw, const float* __restrict__ lnb,
    unsigned short* __restrict__ yzb) {
    const int d = threadIdx.x;
    const int bp = blockIdx.x;            // [0, 32768)
    const int b = bp >> 12;               // [0, 8)
    const int p = bp & 4095;
    const float v =
        (float)ysp[(((size_t)(b << 1)) << 20) + (size_t)p * DDIM + d] +
        (float)ysp[(((size_t)(b << 1) + 1) << 20) + (size_t)p * DDIM + d];

    __shared__ float red[4];
    float s = v;
    #pragma unroll
    for (int o = 32; o > 0; o >>= 1) s += __shfl_xor(s, o);
    const int wave = threadIdx.x >> 6;
    if ((threadIdx.x & 63) == 0) red[wave] = s;
    __syncthreads();
    const float mu = (red[0] + red[1] + red[2] + red[3]) * (1.f / 256.f);
    __syncthreads();
    const float dv = v - mu;
    float s2 = dv * dv;
    #pragma unroll
    for (int o = 32; o > 0; o >>= 1) s2 += __shfl_xor(s2, o);
    if ((threadIdx.x & 63) == 0) red[wave] = s2;
    __syncthreads();
    const float var = (red[0] + red[1] + red[2] + red[3]) * (1.f / 256.f);
    const float y = dv * rsqrtf(var + 1e-5f) * lnw[d] + lnb[d];
    yzb[(size_t)bp * DDIM + d] = f2b(y * b2f(z[(size_t)bp * DDIM + d]));
}

// ---------------------------------------------------------------------------
extern "C" void kernel_launch(void* const* d_in, const int* in_sizes, int n_in,
                              void* d_out, int out_size, void* d_ws, size_t ws_size,
                              hipStream_t stream) {
    const float* xin0  = (const float*)d_in[0];
    const float* xin1  = (const float*)d_in[1];
    const float* inw0  = (const float*)d_in[2];
    const float* inw1  = (const float*)d_in[3];
    const float* convw0 = (const float*)d_in[4];
    const float* convb0 = (const float*)d_in[5];
    const float* convw1 = (const float*)d_in[6];
    const float* convb1 = (const float*)d_in[7];
    const float* xpw   = (const float*)d_in[8];
    const float* dtw   = (const float*)d_in[9];
    const float* dtb   = (const float*)d_in[10];
    const float* Alogs = (const float*)d_in[11];
    const float* Dsv   = (const float*)d_in[12];
    const float* lnw   = (const float*)d_in[13];
    const float* lnb   = (const float*)d_in[14];
    const float* outw0 = (const float*)d_in[15];
    const float* outw1 = (const float*)d_in[16];

    float* ws = (float*)d_ws;
    // layout (float offsets), total 35,770,368 floats = 143.1 MB:
    float* xc_raw  = ws + 0;             // 8,388,608  in_proj xc (dead after conv)
    f16*   ysp     = (f16*)(ws + 0);     //            16 f16 planes (scanC->merge)
    unsigned short* zbuf = (unsigned short*)(ws + 8388608);  // 8.39M bf16
    float* xc_conv = ws + 12582912;      // 8,388,608  conv out (scan input)
    f16*   projh   = (f16*)(ws + 20971520); // 5.24M f16 (x_proj out)
    unsigned short* yzbf = (unsigned short*)(ws + 23068672); // after proj
    f16*   hendH0  = (f16*)(ws + 26214400); // 16.78M f16 (in-place hend->H0)
    float* cumd    = ws + 34603008;      // 1,048,576
    unsigned short* wreg = (unsigned short*)(ws + 35651584); // 237,568 bf16
    unsigned short* wbf_in0  = wreg + 0;
    unsigned short* wbf_in1  = wreg + 65536;
    unsigned short* wbf_xp   = wreg + 131072;
    unsigned short* wbf_out0 = wreg + 172032;
    unsigned short* wbf_out1 = wreg + 204800;
    float* outp = (float*)d_out;

    // 1: all weight conversions (one launch)
    cvt_all<<<116, 256, 0, stream>>>(inw0, inw1, xpw, outw0, outw1, wreg);
    // 2: in_proj, both streams (M=32768, N=512, K=128), fp32-A staging
    gemm_bf<1, true><<<dim3(4, 256), 256, 0, stream>>>(
        nullptr, xin0, xin1, wbf_in0, wbf_in1, xc_raw, zbuf, 512, 128, 16384);
    // 3: depthwise conv + silu (both streams)
    dwconv_silu<<<32768, 256, 0, stream>>>(xc_raw, convw0, convb0,
                                           convw1, convb1, xc_conv);
    // 4: x_proj (M=32768, N=160, K=256), fp32-A staging, f16 output
    gemm_bf<3, true><<<dim3(2, 256), 256, 0, stream>>>(
        nullptr, xc_conv, xc_conv, wbf_xp, wbf_xp, nullptr,
        (unsigned short*)projh, 160, 256, 1 << 30);
    // 5: chunk-local scans, pair-fused + strided + prefetched
    scanA2T<0><<<8 * NCH, 256, 0, stream>>>(xc_conv, projh, Alogs, dtw, dtb,
                                            hendH0, cumd);
    scanA2T<1><<<8 * NCH, 256, 0, stream>>>(xc_conv, projh, Alogs, dtw, dtb,
                                            hendH0, cumd);
    // 6: inter-chunk recurrence
    scanB<<<512, 256, 0, stream>>>(hendH0, cumd, Alogs);
    // 7: final chunk scans, pair-fused + strided + prefetched
    scanC2T<0><<<8 * NCH, 256, 0, stream>>>(xc_conv, projh, Alogs, dtw, dtb,
                                            Dsv, hendH0, ysp);
    scanC2T<1><<<8 * NCH, 256, 0, stream>>>(xc_conv, projh, Alogs, dtw, dtb,
                                            Dsv, hendH0, ysp);
    // 8: merge pair-planes + LN + gate -> bf16
    merge_ln<<<32768, 256, 0, stream>>>(ysp, zbuf, lnw, lnb, yzbf);
    // 9: out_proj (M=32768, N=128, K=256), per-stream W and output offset
    gemm_bf<2, false><<<dim3(1, 256), 256, 0, stream>>>(
        yzbf, nullptr, nullptr, wbf_out0, wbf_out1, outp, nullptr,
        128, 256, 16384);
}

// Round 11
// 273.439 us; speedup vs baseline: 1.2969x; 1.2969x over previous
//
#include <hip/hip_runtime.h>
#include <hip/hip_bf16.h>
#include <math.h>

// Problem constants (B=4, H=W=64, C=128, DI=256, N=16, R=8, K=4)
// BATCHED over the 2 streams: 8 images, 32768 rows, 32 bk channel-groups.
#define DDIM 256
#define NCH  128
#define LCH  32

typedef __attribute__((ext_vector_type(8))) short bf8_t;
typedef __attribute__((ext_vector_type(4))) float f32x4;
typedef __attribute__((ext_vector_type(8))) unsigned short u16x8;
typedef _Float16 f16;
typedef __attribute__((ext_vector_type(2))) _Float16 f16x2;

__device__ __forceinline__ float silu_f(float x) {
    return x / (1.f + __expf(-x));
}
__device__ __forceinline__ float softplus_f(float x) {
    return fmaxf(x, 0.f) + __logf(1.f + __expf(-fabsf(x)));
}
__device__ __forceinline__ unsigned short f2b(float x) {
    union { __hip_bfloat16 h; unsigned short u; } v;
    v.h = __float2bfloat16(x);
    return v.u;
}
__device__ __forceinline__ float b2f(unsigned short u) {
    union { float f; unsigned int i; } v;
    v.i = ((unsigned int)u) << 16;
    return v.f;
}
__device__ __forceinline__ int perm_idx(int k, int l) {
    switch (k & 3) {
        case 0: return l;
        case 1: return ((l & 63) << 6) | (l >> 6);
        case 2: return 4095 - l;
        default: { int lr = 4095 - l; return ((lr & 63) << 6) | (lr >> 6); }
    }
}
// ---- packed f16 helpers -------------------------------------------------
__device__ __forceinline__ f16x2 pkrtz(float a, float b) {
    return __builtin_bit_cast(f16x2, __builtin_amdgcn_cvt_pkrtz(a, b));
}
__device__ __forceinline__ f16x2 bch(unsigned v) {
    return __builtin_bit_cast(f16x2, v);
}
__device__ __forceinline__ unsigned bcu(f16x2 v) {
    return __builtin_bit_cast(unsigned, v);
}
__device__ __forceinline__ f16x2 pk_fma_h(f16x2 a, f16x2 b, f16x2 c) {
    f16x2 d;
    asm("v_pk_fma_f16 %0, %1, %2, %3" : "=v"(d) : "v"(a), "v"(b), "v"(c));
    return d;
}
__device__ __forceinline__ float dot2_h(f16x2 a, f16x2 b, float c) {
    float d;
    asm("v_dot2_f32_f16 %0, %1, %2, %3" : "=v"(d) : "v"(a), "v"(b), "v"(c));
    return d;
}
__device__ __forceinline__ bool geom_check(const float* Alogs, int kd, float& a0) {
    a0 = -__expf(Alogs[(size_t)kd * 16]);
    bool g = true;
    #pragma unroll
    for (int n = 1; n < 16; ++n) {
        const float an = -__expf(Alogs[(size_t)kd * 16 + n]);
        const float rr = a0 * (float)(n + 1);
        g = g && (fabsf(an - rr) <= 1e-4f * fabsf(rr));
    }
    return g;
}
// stride in spatial index per scan step for direction k (within a chunk)
__device__ __forceinline__ int dir_stride(int k) {
    const int m = (k & 1) ? 64 : 1;
    return (k & 2) ? -m : m;
}

// ---------------------------------------------------------------------------
// Convert all 5 weight tensors fp32->bf16 in one launch.
// ---------------------------------------------------------------------------
__global__ __launch_bounds__(256) void cvt_all(
    const float* __restrict__ s0, const float* __restrict__ s1,
    const float* __restrict__ s2, const float* __restrict__ s3,
    const float* __restrict__ s4, unsigned short* __restrict__ w) {
    const int i = blockIdx.x * 256 + threadIdx.x;
    const float* src; size_t so, oo;
    if (i < 8192)       { src = s0; so = i;         oo = 0; }
    else if (i < 16384) { src = s1; so = i - 8192;  oo = 65536; }
    else if (i < 21504) { src = s2; so = i - 16384; oo = 131072; }
    else if (i < 25600) { src = s3; so = i - 21504; oo = 172032; }
    else if (i < 29696) { src = s4; so = i - 25600; oo = 204800; }
    else return;
    const float4 a = ((const float4*)src)[so * 2];
    const float4 b = ((const float4*)src)[so * 2 + 1];
    u16x8 r;
    r[0] = f2b(a.x); r[1] = f2b(a.y); r[2] = f2b(a.z); r[3] = f2b(a.w);
    r[4] = f2b(b.x); r[5] = f2b(b.y); r[6] = f2b(b.z); r[7] = f2b(b.w);
    *(u16x8*)(w + oo + so * 8) = r;
}

// ---------------------------------------------------------------------------
// bf16 MFMA GEMM (batched 2-stream): out[m,n] = sum_k A[m,k] * W[n,k].
// EPI=0: plain f32. EPI=1: in_proj split (xc f32 | silu->bf16 z).
// EPI=2: out_proj per-stream offset. EPI=3: f16 store (x_proj).
// ---------------------------------------------------------------------------
template <int EPI, bool AF32>
__global__ __launch_bounds__(256) void gemm_bf(
    const unsigned short* __restrict__ A,
    const float* __restrict__ Af0, const float* __restrict__ Af1,
    const unsigned short* __restrict__ W0, const unsigned short* __restrict__ W1,
    float* __restrict__ out0, unsigned short* __restrict__ out1b,
    int N, int K, int msplit) {
    __shared__ unsigned short As[128][40];
    __shared__ unsigned short Bs[128][40];
    const int tid = threadIdx.x;
    const int lane = tid & 63;
    const int wid = tid >> 6;
    const int wr = wid >> 1, wc = wid & 1;
    const int m0 = blockIdx.y << 7, n0 = blockIdx.x << 7;
    const int sidx = (m0 >= msplit) ? 1 : 0;
    const int rbase = sidx ? msplit : 0;
    const float* Af = sidx ? Af1 : Af0;
    const unsigned short* W = sidx ? W1 : W0;
    const int r = lane & 15, g = lane >> 4;
    f32x4 acc[4][4];
    #pragma unroll
    for (int i = 0; i < 4; ++i)
        #pragma unroll
        for (int j = 0; j < 4; ++j) acc[i][j] = (f32x4){0.f, 0.f, 0.f, 0.f};
    const int row0 = tid >> 2;       // 0..63
    const int cc = (tid & 3) << 3;   // 0,8,16,24

    for (int k0 = 0; k0 < K; k0 += 32) {
        #pragma unroll
        for (int h = 0; h < 2; ++h) {
            const int row = row0 + (h << 6);
            u16x8 va;
            if (AF32) {
                const float* ap = Af + (size_t)(m0 + row - rbase) * K + k0 + cc;
                const float4 a0 = *(const float4*)ap;
                const float4 a1 = *(const float4*)(ap + 4);
                va[0] = f2b(a0.x); va[1] = f2b(a0.y);
                va[2] = f2b(a0.z); va[3] = f2b(a0.w);
                va[4] = f2b(a1.x); va[5] = f2b(a1.y);
                va[6] = f2b(a1.z); va[7] = f2b(a1.w);
            } else {
                va = *(const u16x8*)(A + (size_t)(m0 + row) * K + k0 + cc);
            }
            *(u16x8*)(&As[row][cc]) = va;
            const int nrow = n0 + row;
            u16x8 vb = (u16x8){0, 0, 0, 0, 0, 0, 0, 0};
            if (nrow < N) vb = *(const u16x8*)(W + (size_t)nrow * K + k0 + cc);
            *(u16x8*)(&Bs[row][cc]) = vb;
        }
        __syncthreads();
        bf8_t af[4], bfr[4];
        #pragma unroll
        for (int i = 0; i < 4; ++i)
            af[i] = *(const bf8_t*)(&As[(wr << 6) + (i << 4) + r][g << 3]);
        #pragma unroll
        for (int j = 0; j < 4; ++j)
            bfr[j] = *(const bf8_t*)(&Bs[(wc << 6) + (j << 4) + r][g << 3]);
        #pragma unroll
        for (int i = 0; i < 4; ++i)
            #pragma unroll
            for (int j = 0; j < 4; ++j)
                acc[i][j] = __builtin_amdgcn_mfma_f32_16x16x32_bf16(
                    af[i], bfr[j], acc[i][j], 0, 0, 0);
        __syncthreads();
    }
    // epilogue: C/D layout col=lane&15, row=(lane>>4)*4+reg
    #pragma unroll
    for (int i = 0; i < 4; ++i) {
        const int mrow = m0 + (wr << 6) + (i << 4) + (g << 2);
        #pragma unroll
        for (int j = 0; j < 4; ++j) {
            const int col = n0 + (wc << 6) + (j << 4) + r;
            if (EPI != 1 && col >= N) continue;
            #pragma unroll
            for (int q = 0; q < 4; ++q) {
                const float v = acc[i][j][q];
                const int mm = mrow + q;
                if (EPI == 0) {
                    out0[(size_t)mm * N + col] = v;
                } else if (EPI == 1) {
                    if (col < 256) out0[((size_t)mm << 8) + col] = v;
                    else out1b[((size_t)mm << 8) + (col - 256)] = f2b(silu_f(v));
                } else if (EPI == 2) {
                    out0[(size_t)sidx * 2097152 +
                         ((size_t)(mm - rbase) << 7) + col] = v;
                } else {
                    ((f16*)out1b)[(size_t)mm * N + col] = (f16)v;
                }
            }
        }
    }
}

// ---------------------------------------------------------------------------
// Depthwise 3x3 conv (SAME) + bias + SiLU, 4 w-positions per thread.
// blockIdx = b*1024 + h*16 + w4; threads = d. 18 loads -> 4 outputs.
// ---------------------------------------------------------------------------
__global__ __launch_bounds__(256) void dwconv_silu(
    const float* __restrict__ in,
    const float* __restrict__ w0, const float* __restrict__ b0,
    const float* __restrict__ w1, const float* __restrict__ b1,
    float* __restrict__ outf) {
    const int d = threadIdx.x;
    const int blk = blockIdx.x;           // [0, 8192)
    const int b = blk >> 10;              // [0, 8)
    const int rem = blk & 1023;
    const int h = rem >> 4;               // [0, 64)
    const int w4 = rem & 15;              // [0, 16)
    const int wc0 = w4 << 2;
    const float* w = (b >= 4) ? w1 : w0;
    const float* biasp = (b >= 4) ? b1 : b0;

    float v[3][6];
    #pragma unroll
    for (int r = 0; r < 3; ++r) {
        const int hh = h + r - 1;
        const bool hok = (hh >= 0) && (hh < 64);
        #pragma unroll
        for (int c6 = 0; c6 < 6; ++c6) {
            const int ww = wc0 + c6 - 1;
            const bool ok = hok && (ww >= 0) && (ww < 64);
            v[r][c6] = ok ?
                in[(size_t)(((b << 12) + (hh << 6) + ww)) * DDIM + d] : 0.f;
        }
    }
    float wg[9];
    #pragma unroll
    for (int i = 0; i < 9; ++i) wg[i] = w[d * 9 + i];
    const float bias = biasp[d];
    #pragma unroll
    for (int j = 0; j < 4; ++j) {
        float acc = bias;
        #pragma unroll
        for (int kh = 0; kh < 3; ++kh)
            #pragma unroll
            for (int kw = 0; kw < 3; ++kw)
                acc = fmaf(v[kh][j + kw], wg[kh * 3 + kw], acc);
        outf[(size_t)(((b << 12) + (h << 6) + wc0 + j)) * DDIM + d] =
            silu_f(acc);
    }
}

// ---------------------------------------------------------------------------
// scan chain A (one chunk, one direction): runtime stride ss, register
// double-buffered prefetch of the proj row (3 uint4) + u.
// Writes h_end (f16) and cum delta.
// ---------------------------------------------------------------------------
__device__ __forceinline__ void chainA(
    const int ss, const int k, const int kd, const int bk, const int chunk,
    const int bpp0, const int d,
    const float* __restrict__ xc, const f16* __restrict__ proj,
    const float* __restrict__ Alogs, const float* __restrict__ dtw,
    const float* __restrict__ dtb,
    f16* __restrict__ hend, float* __restrict__ cumd) {
    float a0;
    const bool geom = geom_check(Alogs, kd, a0);
    const float4 w0f = *(const float4*)(dtw + (size_t)kd * 8);
    const float4 w1f = *(const float4*)(dtw + (size_t)kd * 8 + 4);
    const float bias = dtb[kd];
    float cum = 0.f;
    const size_t o32 = ((size_t)(chunk * 32 + bk) * DDIM + d) * 8;  // uint units
    const int pstep = ss * 80;                 // proj row stride (uints)
    const ptrdiff_t ustep = (ptrdiff_t)ss * DDIM;

    if (geom) {
        const f16x2 wh[4] = {pkrtz(w0f.x, w0f.y), pkrtz(w0f.z, w0f.w),
                             pkrtz(w1f.x, w1f.y), pkrtz(w1f.z, w1f.w)};
        f16x2 h[8];
        #pragma unroll
        for (int j = 0; j < 8; ++j) h[j] = (f16x2){(f16)0.f, (f16)0.f};
        const unsigned* prow =
            (const unsigned*)(proj + (size_t)bpp0 * 160 + k * 40);
        const float* up = xc + (size_t)bpp0 * DDIM + d;
        uint4 dt_n = *(const uint4*)prow;
        uint4 B0_n = *(const uint4*)(prow + 4);
        uint4 B1_n = *(const uint4*)(prow + 8);
        float u_n = *up;
        #pragma unroll 4
        for (int t = 0; t < LCH; ++t) {
            const uint4 dt4 = dt_n, B0 = B0_n, B1 = B1_n;
            const float u = u_n;
            if (t < LCH - 1) {
                prow += pstep;
                up += ustep;
                dt_n = *(const uint4*)prow;
                B0_n = *(const uint4*)(prow + 4);
                B1_n = *(const uint4*)(prow + 8);
                u_n = *up;
            }
            float x = bias;
            x = dot2_h(bch(dt4.x), wh[0], x);
            x = dot2_h(bch(dt4.y), wh[1], x);
            x = dot2_h(bch(dt4.z), wh[2], x);
            x = dot2_h(bch(dt4.w), wh[3], x);
            const float delta = softplus_f(x);
            const float du = delta * u;
            cum += delta;
            const float e1 = __expf(delta * a0);
            const float e2 = e1 * e1;
            const f16x2 s2 = pkrtz(e2, e2);
            f16x2 dA[8];
            dA[0] = pkrtz(e1, e2);
            #pragma unroll
            for (int j = 1; j < 8; ++j) dA[j] = dA[j - 1] * s2;
            const f16x2 du2 = pkrtz(du, du);
            const unsigned Bw[8] = {B0.x, B0.y, B0.z, B0.w,
                                    B1.x, B1.y, B1.z, B1.w};
            #pragma unroll
            for (int j = 0; j < 8; ++j)
                h[j] = pk_fma_h(dA[j], h[j], du2 * bch(Bw[j]));
        }
        const uint4 s0 = make_uint4(bcu(h[0]), bcu(h[1]), bcu(h[2]), bcu(h[3]));
        const uint4 s1 = make_uint4(bcu(h[4]), bcu(h[5]), bcu(h[6]), bcu(h[7]));
        *(uint4*)((unsigned*)hend + o32) = s0;
        *(uint4*)((unsigned*)hend + o32 + 4) = s1;
    } else {
        float w8[8] = {w0f.x, w0f.y, w0f.z, w0f.w, w1f.x, w1f.y, w1f.z, w1f.w};
        float h[16];
        #pragma unroll
        for (int n = 0; n < 16; ++n) h[n] = 0.f;
        int bpp = bpp0;
        for (int t = 0; t < LCH; ++t) {
            const f16* pr = proj + (size_t)bpp * 160 + k * 40;
            float x = bias;
            #pragma unroll
            for (int r = 0; r < 8; ++r) x = fmaf((float)pr[r], w8[r], x);
            const float delta = softplus_f(x);
            const float u = xc[(size_t)bpp * DDIM + d];
            const float du = delta * u;
            cum += delta;
            #pragma unroll
            for (int n = 0; n < 16; ++n) {
                const float an = -__expf(Alogs[(size_t)kd * 16 + n]);
                h[n] = fmaf(__expf(delta * an), h[n], du * (float)pr[8 + n]);
            }
            bpp += ss;
        }
        #pragma unroll
        for (int n = 0; n < 16; ++n)
            ((f16*)hend)[o32 * 2 + n] = (f16)h[n];
    }
    cumd[(size_t)(chunk * 32 + bk) * DDIM + d] = cum;
}

// scanA: one chunk per block, 4096 blocks (full grid, 8 blocks/CU).
__global__ __launch_bounds__(256) void scanA(
    const float* __restrict__ xc, const f16* __restrict__ proj,
    const float* __restrict__ Alogs, const float* __restrict__ dtw,
    const float* __restrict__ dtb,
    f16* __restrict__ hend, float* __restrict__ cumd) {
    const int d = threadIdx.x;
    const int blk = blockIdx.x;
    const int c = blk & (NCH - 1);
    const int bk = blk >> 7;              // [0, 32)
    const int k = bk & 3;
    const int b = bk >> 2;                // [0, 8)
    const int ss = dir_stride(k);
    const int p0 = perm_idx(k, c * LCH);
    chainA(ss, k, (k << 8) + d, bk, c, (b << 12) + p0, d,
           xc, proj, Alogs, dtw, dtb, hend, cumd);
}

// ---------------------------------------------------------------------------
// Scan phase B: inter-chunk recurrence over 131072 states, IN PLACE on the
// fp16 buffer (read hend[c], then overwrite slot c with H0[c]).
// ---------------------------------------------------------------------------
__global__ __launch_bounds__(256) void scanB(
    f16* __restrict__ hh, const float* __restrict__ cumd,
    const float* __restrict__ Alogs) {
    const int tid = blockIdx.x * 256 + threadIdx.x;   // [0, 131072)
    const int n = tid & 15;
    const int d = (tid >> 4) & 255;
    const int bk = tid >> 12;
    const int k = bk & 3;
    const float a = -__expf(Alogs[(size_t)(((k << 8) + d)) * 16 + n]);
    const int cdix = tid >> 4;                        // bk*256+d
    float H = 0.f;
    for (int c = 0; c < NCH; c += 4) {
        float tmp[4], cd[4];
        #pragma unroll
        for (int j = 0; j < 4; ++j) {
            tmp[j] = (float)hh[(size_t)(c + j) * 131072 + tid];
            cd[j] = cumd[(size_t)(c + j) * 8192 + cdix];
        }
        #pragma unroll
        for (int j = 0; j < 4; ++j) {
            hh[(size_t)(c + j) * 131072 + tid] = (f16)H;
            H = fmaf(__expf(cd[j] * a), H, tmp[j]);
        }
    }
}

// ---------------------------------------------------------------------------
// scan chain C (one chunk, one direction): runtime stride ss, register
// double-buffered prefetch of proj row (5 uint4) + u. EMIT=0: y->ybuf[t][d].
// EMIT=1: emit ybuf[31-t][d] + y to ysp (pointer-strided).
// ---------------------------------------------------------------------------
template <int EMIT>
__device__ __forceinline__ void chainC(
    const int ss, const int k, const int kd, const int bk, const int chunk,
    const int bpp0, const int d,
    const float* __restrict__ xc, const f16* __restrict__ proj,
    const float* __restrict__ Alogs, const float* __restrict__ dtw,
    const float* __restrict__ dtb, const float* __restrict__ Dsv,
    const f16* __restrict__ H0, f16* __restrict__ ysp,
    f16 (*ybuf)[256], const size_t planeBase) {
    float a0;
    const bool geom = geom_check(Alogs, kd, a0);
    const float4 w0f = *(const float4*)(dtw + (size_t)kd * 8);
    const float4 w1f = *(const float4*)(dtw + (size_t)kd * 8 + 4);
    const float bias = dtb[kd];
    const float Dd = Dsv[kd];
    const size_t o32 = ((size_t)(chunk * 32 + bk) * DDIM + d) * 8;  // uint units
    const int p0 = bpp0 & 4095;
    f16* yp = ysp + planeBase + (size_t)p0 * DDIM + d;
    const int pstep = ss * 80;
    const ptrdiff_t ustep = (ptrdiff_t)ss * DDIM;

    if (geom) {
        const f16x2 wh[4] = {pkrtz(w0f.x, w0f.y), pkrtz(w0f.z, w0f.w),
                             pkrtz(w1f.x, w1f.y), pkrtz(w1f.z, w1f.w)};
        f16x2 h[8];
        {
            const uint4 r0 = *(const uint4*)((const unsigned*)H0 + o32);
            const uint4 r1 = *(const uint4*)((const unsigned*)H0 + o32 + 4);
            h[0] = bch(r0.x); h[1] = bch(r0.y); h[2] = bch(r0.z); h[3] = bch(r0.w);
            h[4] = bch(r1.x); h[5] = bch(r1.y); h[6] = bch(r1.z); h[7] = bch(r1.w);
        }
        const unsigned* prow =
            (const unsigned*)(proj + (size_t)bpp0 * 160 + k * 40);
        const float* up = xc + (size_t)bpp0 * DDIM + d;
        uint4 dt_n = *(const uint4*)prow;
        uint4 B0_n = *(const uint4*)(prow + 4);
        uint4 B1_n = *(const uint4*)(prow + 8);
        uint4 C0_n = *(const uint4*)(prow + 12);
        uint4 C1_n = *(const uint4*)(prow + 16);
        float u_n = *up;
        #pragma unroll 4
        for (int t = 0; t < LCH; ++t) {
            const uint4 dt4 = dt_n, B0 = B0_n, B1 = B1_n, C0 = C0_n, C1 = C1_n;
            const float u = u_n;
            if (t < LCH - 1) {
                prow += pstep;
                up += ustep;
                dt_n = *(const uint4*)prow;
                B0_n = *(const uint4*)(prow + 4);
                B1_n = *(const uint4*)(prow + 8);
                C0_n = *(const uint4*)(prow + 12);
                C1_n = *(const uint4*)(prow + 16);
                u_n = *up;
            }
            float x = bias;
            x = dot2_h(bch(dt4.x), wh[0], x);
            x = dot2_h(bch(dt4.y), wh[1], x);
            x = dot2_h(bch(dt4.z), wh[2], x);
            x = dot2_h(bch(dt4.w), wh[3], x);
            const float delta = softplus_f(x);
            const float du = delta * u;
            const float e1 = __expf(delta * a0);
            const float e2 = e1 * e1;
            const f16x2 s2 = pkrtz(e2, e2);
            f16x2 dA[8];
            dA[0] = pkrtz(e1, e2);
            #pragma unroll
            for (int j = 1; j < 8; ++j) dA[j] = dA[j - 1] * s2;
            const f16x2 du2 = pkrtz(du, du);
            const unsigned Bw[8] = {B0.x, B0.y, B0.z, B0.w,
                                    B1.x, B1.y, B1.z, B1.w};
            const unsigned Cw[8] = {C0.x, C0.y, C0.z, C0.w,
                                    C1.x, C1.y, C1.z, C1.w};
            float y = 0.f;
            #pragma unroll
            for (int j = 0; j < 8; ++j) {
                h[j] = pk_fma_h(dA[j], h[j], du2 * bch(Bw[j]));
                y = dot2_h(h[j], bch(Cw[j]), y);
            }
            y = fmaf(Dd, u, y);
            if (EMIT == 0) ybuf[t][d] = (f16)y;
            else *yp = (f16)(y + (float)ybuf[31 - t][d]);
            yp += ustep;
        }
    } else {
        float w8[8] = {w0f.x, w0f.y, w0f.z, w0f.w, w1f.x, w1f.y, w1f.z, w1f.w};
        float h[16];
        #pragma unroll
        for (int n = 0; n < 16; ++n)
            h[n] = (float)((const f16*)H0)[o32 * 2 + n];
        int bpp = bpp0;
        for (int t = 0; t < LCH; ++t) {
            const f16* pr = proj + (size_t)bpp * 160 + k * 40;
            float x = bias;
            #pragma unroll
            for (int r = 0; r < 8; ++r) x = fmaf((float)pr[r], w8[r], x);
            const float delta = softplus_f(x);
            const float u = xc[(size_t)bpp * DDIM + d];
            const float du = delta * u;
            float y = 0.f;
            #pragma unroll
            for (int n = 0; n < 16; ++n) {
                const float an = -__expf(Alogs[(size_t)kd * 16 + n]);
                h[n] = fmaf(__expf(delta * an), h[n], du * (float)pr[8 + n]);
                y = fmaf(h[n], (float)pr[24 + n], y);
            }
            y = fmaf(Dd, u, y);
            if (EMIT == 0) ybuf[t][d] = (f16)y;
            else *yp = (f16)(y + (float)ybuf[31 - t][d]);
            yp += ustep;
            bpp += ss;
        }
    }
}

// Pair-fused scanC: (k=pair, chunk c, +S) buffers y; (k=pair+2, chunk
// NCH-1-c, -S) emits pair-sums. 2048 blocks (8/CU).
// blockIdx = (b*2+pair)*NCH + c, b in [0,8).
__global__ __launch_bounds__(256) void scanC2(
    const float* __restrict__ xc, const f16* __restrict__ proj,
    const float* __restrict__ Alogs, const float* __restrict__ dtw,
    const float* __restrict__ dtb, const float* __restrict__ Dsv,
    const f16* __restrict__ H0, f16* __restrict__ ysp) {
    __shared__ f16 ybuf[LCH][256];
    const int d = threadIdx.x;
    const int blk = blockIdx.x;
    const int c = blk & (NCH - 1);
    const int bp2 = blk >> 7;             // [0, 16)
    const int pair = bp2 & 1;
    const int b = bp2 >> 1;               // [0, 8)
    const int S = pair ? 64 : 1;
    const int p0 = perm_idx(pair, c * LCH);
    const int bpp0 = (b << 12) + p0;
    const size_t planeBase = (size_t)bp2 << 20;
    chainC<0>(S, pair, (pair << 8) + d, (b << 2) + pair, c, bpp0, d,
              xc, proj, Alogs, dtw, dtb, Dsv, H0, ysp, ybuf, planeBase);
    chainC<1>(-S, pair + 2, ((pair + 2) << 8) + d, (b << 2) + pair + 2,
              NCH - 1 - c, bpp0 + 31 * S, d,
              xc, proj, Alogs, dtw, dtb, Dsv, H0, ysp, ybuf, planeBase);
}

// ---------------------------------------------------------------------------
// Merge 2 pair-planes (f16) + LayerNorm(D) + gate with bf16 z -> bf16 yz.
// ---------------------------------------------------------------------------
__global__ __launch_bounds__(256) void merge_ln(
    const f16* __restrict__ ysp, const unsigned short* __restrict__ z,
    const float* __restrict__ lnw, const float* __restrict__ lnb,
    unsigned short* __restrict__ yzb) {
    const int d = threadIdx.x;
    const int bp = blockIdx.x;            // [0, 32768)
    const int b = bp >> 12;               // [0, 8)
    const int p = bp & 4095;
    const float v =
        (float)ysp[(((size_t)(b << 1)) << 20) + (size_t)p * DDIM + d] +
        (float)ysp[(((size_t)(b << 1) + 1) << 20) + (size_t)p * DDIM + d];

    __shared__ float red[4];
    float s = v;
    #pragma unroll
    for (int o = 32; o > 0; o >>= 1) s += __shfl_xor(s, o);
    const int wave = threadIdx.x >> 6;
    if ((threadIdx.x & 63) == 0) red[wave] = s;
    __syncthreads();
    const float mu = (red[0] + red[1] + red[2] + red[3]) * (1.f / 256.f);
    __syncthreads();
    const float dv = v - mu;
    float s2 = dv * dv;
    #pragma unroll
    for (int o = 32; o > 0; o >>= 1) s2 += __shfl_xor(s2, o);
    if ((threadIdx.x & 63) == 0) red[wave] = s2;
    __syncthreads();
    const float var = (red[0] + red[1] + red[2] + red[3]) * (1.f / 256.f);
    const float y = dv * rsqrtf(var + 1e-5f) * lnw[d] + lnb[d];
    yzb[(size_t)bp * DDIM + d] = f2b(y * b2f(z[(size_t)bp * DDIM + d]));
}

// ---------------------------------------------------------------------------
extern "C" void kernel_launch(void* const* d_in, const int* in_sizes, int n_in,
                              void* d_out, int out_size, void* d_ws, size_t ws_size,
                              hipStream_t stream) {
    const float* xin0  = (const float*)d_in[0];
    const float* xin1  = (const float*)d_in[1];
    const float* inw0  = (const float*)d_in[2];
    const float* inw1  = (const float*)d_in[3];
    const float* convw0 = (const float*)d_in[4];
    const float* convb0 = (const float*)d_in[5];
    const float* convw1 = (const float*)d_in[6];
    const float* convb1 = (const float*)d_in[7];
    const float* xpw   = (const float*)d_in[8];
    const float* dtw   = (const float*)d_in[9];
    const float* dtb   = (const float*)d_in[10];
    const float* Alogs = (const float*)d_in[11];
    const float* Dsv   = (const float*)d_in[12];
    const float* lnw   = (const float*)d_in[13];
    const float* lnb   = (const float*)d_in[14];
    const float* outw0 = (const float*)d_in[15];
    const float* outw1 = (const float*)d_in[16];

    float* ws = (float*)d_ws;
    // layout (float offsets), total 35,770,368 floats = 143.1 MB:
    float* xc_raw  = ws + 0;             // 8,388,608  in_proj xc (dead after conv)
    f16*   ysp     = (f16*)(ws + 0);     //            16 f16 planes (scanC->merge)
    unsigned short* zbuf = (unsigned short*)(ws + 8388608);  // 8.39M bf16
    float* xc_conv = ws + 12582912;      // 8,388,608  conv out (scan input)
    f16*   projh   = (f16*)(ws + 20971520); // 5.24M f16 (x_proj out)
    unsigned short* yzbf = (unsigned short*)(ws + 23068672); // after proj
    f16*   hendH0  = (f16*)(ws + 26214400); // 16.78M f16 (in-place hend->H0)
    float* cumd    = ws + 34603008;      // 1,048,576
    unsigned short* wreg = (unsigned short*)(ws + 35651584); // 237,568 bf16
    unsigned short* wbf_in0  = wreg + 0;
    unsigned short* wbf_in1  = wreg + 65536;
    unsigned short* wbf_xp   = wreg + 131072;
    unsigned short* wbf_out0 = wreg + 172032;
    unsigned short* wbf_out1 = wreg + 204800;
    float* outp = (float*)d_out;

    // 1: all weight conversions (one launch)
    cvt_all<<<116, 256, 0, stream>>>(inw0, inw1, xpw, outw0, outw1, wreg);
    // 2: in_proj, both streams (M=32768, N=512, K=128), fp32-A staging
    gemm_bf<1, true><<<dim3(4, 256), 256, 0, stream>>>(
        nullptr, xin0, xin1, wbf_in0, wbf_in1, xc_raw, zbuf, 512, 128, 16384);
    // 3: depthwise conv + silu (both streams, 4 positions/thread)
    dwconv_silu<<<8192, 256, 0, stream>>>(xc_raw, convw0, convb0,
                                          convw1, convb1, xc_conv);
    // 4: x_proj (M=32768, N=160, K=256), fp32-A staging, f16 output
    gemm_bf<3, true><<<dim3(2, 256), 256, 0, stream>>>(
        nullptr, xc_conv, xc_conv, wbf_xp, wbf_xp, nullptr,
        (unsigned short*)projh, 160, 256, 1 << 30);
    // 5: chunk-local scans (full grid, strided + prefetched)
    scanA<<<32 * NCH, 256, 0, stream>>>(xc_conv, projh, Alogs, dtw, dtb,
                                        hendH0, cumd);
    // 6: inter-chunk recurrence
    scanB<<<512, 256, 0, stream>>>(hendH0, cumd, Alogs);
    // 7: final chunk scans, pair-fused (full grid, strided + prefetched)
    scanC2<<<16 * NCH, 256, 0, stream>>>(xc_conv, projh, Alogs, dtw, dtb,
                                         Dsv, hendH0, ysp);
    // 8: merge pair-planes + LN + gate -> bf16
    merge_ln<<<32768, 256, 0, stream>>>(ysp, zbuf, lnw, lnb, yzbf);
    // 9: out_proj (M=32768, N=128, K=256), per-stream W and output offset
    gemm_bf<2, false><<<dim3(1, 256), 256, 0, stream>>>(
        yzbf, nullptr, nullptr, wbf_out0, wbf_out1, outp, nullptr,
        128, 256, 16384);
}